// Round 2
// baseline (353.069 us; speedup 1.0000x reference)
//
#include <hip/hip_runtime.h>

// Problem constants
constexpr int Bb = 4;     // batch
constexpr int Dd = 256;   // channels
constexpr int Nn = 2048;  // query positions
constexpr int Mm = 2048;  // source positions
constexpr int Hh = 4;     // heads
constexpr int D2 = 512;   // 2*D
constexpr int NT = Bb * Nn;  // 8192 total positions

#define FMAXV 3.402823466e38f

typedef _Float16 half8 __attribute__((ext_vector_type(8)));
typedef _Float16 half4v __attribute__((ext_vector_type(4)));
typedef float f32x4 __attribute__((ext_vector_type(4)));

// ---------------------------------------------------------------------------
// Weight prepack + mask->bitmask pack (unchanged from R1)
// ---------------------------------------------------------------------------
__global__ __launch_bounds__(256)
void prep_weights_kernel(const float* __restrict__ Wq, const float* __restrict__ bq,
                         const float* __restrict__ Wk, const float* __restrict__ bk,
                         const float* __restrict__ Wv, const float* __restrict__ bv,
                         const float* __restrict__ Wm,
                         const float* __restrict__ W1, const float* __restrict__ b1,
                         const float* __restrict__ gamma, const float* __restrict__ beta,
                         const float* __restrict__ rmean, const float* __restrict__ rvar,
                         const float* __restrict__ W2, const float* __restrict__ mask,
                         _Float16* __restrict__ Wqp, float* __restrict__ bqp,
                         _Float16* __restrict__ Wkvp, float* __restrict__ bkvp,
                         _Float16* __restrict__ Wmp,
                         _Float16* __restrict__ W1p, float* __restrict__ b1f,
                         _Float16* __restrict__ W2p,
                         unsigned long long* __restrict__ bmask) {
    const int r = blockIdx.x, t = threadIdx.x;
    if (r < 256) {
        const int h = r >> 6, d = r & 63, so = d * Hh + h;
        Wqp[r * 256 + t] = (_Float16)Wq[so * 256 + t];
        if (t == 0) bqp[r] = bq[so];
    } else if (r < 768) {
        const int rr = r - 256, part = rr >> 8, o = rr & 255;
        const int h = o >> 6, d = o & 63, so = d * Hh + h;
        const float* Ws = part ? Wv : Wk;
        const float* bs = part ? bv : bk;
        Wkvp[rr * 256 + t] = (_Float16)Ws[so * 256 + t];
        if (t == 0) bkvp[rr] = bs[so];
    } else if (r < 1024) {
        const int o = r - 768;
        const int h = t >> 6, d = t & 63, sk = d * Hh + h;
        Wmp[o * 256 + t] = (_Float16)Wm[o * 256 + sk];
    } else if (r < 1536) {
        const int o = r - 1024;
        const float s = gamma[o] * rsqrtf(rvar[o] + 1e-3f);
        W1p[o * 512 + t]       = (_Float16)(W1[o * 512 + t] * s);
        W1p[o * 512 + t + 256] = (_Float16)(W1[o * 512 + t + 256] * s);
        if (t == 0) b1f[o] = (b1[o] - rmean[o]) * s + beta[o];
    } else if (r < 1792) {
        const int o = r - 1536;
        W2p[o * 512 + t]       = (_Float16)W2[o * 512 + t];
        W2p[o * 512 + t + 256] = (_Float16)W2[o * 512 + t + 256];
    } else {
        // bitmask pack: 2048 blocks x 4 waves, one row of mask per wave.
        const int id = r - 1792;               // 0..2047
        const int w = t >> 6, lane = t & 63;
        const int row = id * 4 + w;            // 0..8191  (= b*Nn + n)
        const float* mrow = mask + (size_t)row * Mm;
        unsigned long long* brow = bmask + (size_t)row * (Mm / 64);
        #pragma unroll 4
        for (int word = 0; word < Mm / 64; ++word) {
            const float v = mrow[word * 64 + lane];
            const unsigned long long bits = __ballot(v > 0.f);
            if (lane == 0) brow[word] = bits;
        }
    }
}

// ---------------------------------------------------------------------------
// Activation prepack (unchanged)
// ---------------------------------------------------------------------------
__global__ __launch_bounds__(256)
void prep_x_kernel(const float* __restrict__ x, const float* __restrict__ source,
                   _Float16* __restrict__ Yp, _Float16* __restrict__ Sp) {
    __shared__ _Float16 Ts[64][72];
    const int z = blockIdx.z, b = z >> 1, which = z & 1;
    const float* src = which ? source : x;
    _Float16* dst = which ? Sp : Yp;
    const int stride = which ? 256 : 512;
    const int c0 = blockIdx.y * 64, n0 = blockIdx.x * 64;
    const int t = threadIdx.x;
    const int cl = t >> 2, np = (t & 3) * 16;
    const float* sp = src + ((size_t)b * Dd + c0 + cl) * Nn + n0 + np;
    #pragma unroll
    for (int i = 0; i < 4; ++i) {
        float4 v = *(const float4*)(sp + i * 4);
        Ts[np + i * 4 + 0][cl] = (_Float16)v.x;
        Ts[np + i * 4 + 1][cl] = (_Float16)v.y;
        Ts[np + i * 4 + 2][cl] = (_Float16)v.z;
        Ts[np + i * 4 + 3][cl] = (_Float16)v.w;
    }
    __syncthreads();
    const int nl = t >> 2, cp = (t & 3) * 16;
    half8 a0 = *(const half8*)&Ts[nl][cp];
    half8 a1 = *(const half8*)&Ts[nl][cp + 8];
    _Float16* dp = dst + ((size_t)b * Nn + n0 + nl) * stride + c0 + cp;
    *(half8*)dp = a0;
    *(half8*)(dp + 8) = a1;
}

// ---------------------------------------------------------------------------
// fp16 MFMA GEMM. R2 change: 32x64 tile per wave (was 64x64) -> 2x tiles ->
// 4-8 waves/CU instead of 2-4 (grid was the binding occupancy limit; 2+
// SIMDs/CU sat idle). Same two-stage register ping-pong on K.
// ---------------------------------------------------------------------------
__global__ __launch_bounds__(64)
void gemm16_kernel(const _Float16* __restrict__ A, const _Float16* __restrict__ W,
                   const float* __restrict__ bias,
                   _Float16* __restrict__ dst0, _Float16* __restrict__ dst1,
                   float* __restrict__ dstF,
                   int K, int sA, int sOut, int modeSel, int relu) {
    __shared__ _Float16 Es[16][72];
    const int lane = threadIdx.x & 63, quad = lane >> 4, l16 = lane & 15;
    const int n0 = blockIdx.x * 32;
    const int og0 = blockIdx.y * 64;

    const _Float16* aRow[2];
    const _Float16* bRow[4];
    #pragma unroll
    for (int i = 0; i < 2; ++i)
        aRow[i] = A + (size_t)(n0 + i * 16 + l16) * sA + quad * 8;
    #pragma unroll
    for (int j = 0; j < 4; ++j)
        bRow[j] = W + (size_t)(og0 + j * 16 + l16) * K + quad * 8;

    f32x4 acc[2][4] = {};
    half8 a0[2], b0[4], a1[2], b1[4];
    #pragma unroll
    for (int i = 0; i < 2; ++i) a0[i] = *(const half8*)(aRow[i]);
    #pragma unroll
    for (int j = 0; j < 4; ++j) b0[j] = *(const half8*)(bRow[j]);

    #pragma unroll 1
    for (int k0 = 0; k0 < K; k0 += 64) {
        // prefetch stage 1 (k0+32)
        #pragma unroll
        for (int i = 0; i < 2; ++i) a1[i] = *(const half8*)(aRow[i] + k0 + 32);
        #pragma unroll
        for (int j = 0; j < 4; ++j) b1[j] = *(const half8*)(bRow[j] + k0 + 32);
        // compute stage 0
        #pragma unroll
        for (int i = 0; i < 2; ++i)
            #pragma unroll
            for (int j = 0; j < 4; ++j)
                acc[i][j] = __builtin_amdgcn_mfma_f32_16x16x32_f16(a0[i], b0[j], acc[i][j], 0, 0, 0);
        // prefetch next stage 0 (k0+64)
        if (k0 + 64 < K) {
            #pragma unroll
            for (int i = 0; i < 2; ++i) a0[i] = *(const half8*)(aRow[i] + k0 + 64);
            #pragma unroll
            for (int j = 0; j < 4; ++j) b0[j] = *(const half8*)(bRow[j] + k0 + 64);
        }
        // compute stage 1
        #pragma unroll
        for (int i = 0; i < 2; ++i)
            #pragma unroll
            for (int j = 0; j < 4; ++j)
                acc[i][j] = __builtin_amdgcn_mfma_f32_16x16x32_f16(a1[i], b1[j], acc[i][j], 0, 0, 0);
    }

    float bcol[4];
    #pragma unroll
    for (int j = 0; j < 4; ++j) bcol[j] = bias[og0 + j * 16 + l16];

    int mode = 0, oloc0 = og0;
    if (modeSel == 2) mode = 2;
    else if (modeSel == 1 && og0 >= 256) { mode = 1; oloc0 = og0 - 256; }

    if (mode == 0) {
        #pragma unroll
        for (int i = 0; i < 2; ++i) {
            #pragma unroll
            for (int j = 0; j < 4; ++j)
                #pragma unroll
                for (int reg = 0; reg < 4; ++reg) {
                    float v = acc[i][j][reg] + bcol[j];
                    if (relu) v = fmaxf(v, 0.f);
                    Es[quad * 4 + reg][j * 16 + l16] = (_Float16)v;
                }
            __asm__ volatile("s_waitcnt lgkmcnt(0)" ::: "memory");
            const int row = lane & 15, oseg = (lane >> 4) * 16;
            half8 e0 = *(const half8*)&Es[row][oseg];
            half8 e1 = *(const half8*)&Es[row][oseg + 8];
            _Float16* dp = dst0 + (size_t)(n0 + i * 16 + row) * sOut + oloc0 + oseg;
            *(half8*)dp = e0;
            *(half8*)(dp + 8) = e1;
            __asm__ volatile("s_waitcnt lgkmcnt(0)" ::: "memory");
        }
    } else if (mode == 1) {
        #pragma unroll
        for (int i = 0; i < 2; ++i) {
            const int ng = n0 + i * 16 + quad * 4;
            const int bidx = ng >> 11, m0 = ng & 2047;
            #pragma unroll
            for (int j = 0; j < 4; ++j) {
                const int o = oloc0 + j * 16 + l16;
                half4v pv;
                #pragma unroll
                for (int reg = 0; reg < 4; ++reg) pv[reg] = (_Float16)(acc[i][j][reg] + bcol[j]);
                *(half4v*)(dst1 + ((size_t)bidx * 256 + o) * (size_t)Mm + m0) = pv;
            }
        }
    } else {
        #pragma unroll
        for (int i = 0; i < 2; ++i) {
            const int ng = n0 + i * 16 + quad * 4;
            const int bidx = ng >> 11, m0 = ng & 2047;
            #pragma unroll
            for (int j = 0; j < 4; ++j) {
                const int o = og0 + j * 16 + l16;
                f32x4 v;
                #pragma unroll
                for (int reg = 0; reg < 4; ++reg) v[reg] = acc[i][j][reg] + bcol[j];
                *(f32x4*)(dstF + ((size_t)bidx * 256 + o) * (size_t)Nn + m0) = v;
            }
        }
    }
}

// ---------------------------------------------------------------------------
// MFMA attention, R2: software-pipelined m-loop.
//  - K tiles double-buffered in registers across steps (ping-pong, unroll-2):
//    K(it+1) issues before step(it) runs -> its ~300-500cy L2 latency hides
//    under a full step.
//  - V tile loads issue at the TOP of each step (they were pinned after the
//    Ps roundtrip by the asm "memory" barrier) -> ~400cy of QK+exp+Ps covers
//    them before the PV MFMAs consume them.
//  - Static-max softmax + bitmask retained from R1.
// Grid (N/16, H, B) = 2048 blocks, 256 thr.
// ---------------------------------------------------------------------------
__global__ __launch_bounds__(256)
void attn_mfma_kernel(const _Float16* __restrict__ Qp, const _Float16* __restrict__ Kp,
                      const _Float16* __restrict__ Vt,
                      const unsigned int* __restrict__ bmask,
                      _Float16* __restrict__ msgp) {
    __shared__ __align__(16) _Float16 Ps[4][16][72];   // 9216 B
    __shared__ __align__(16) _Float16 Osw[4][16][68];  // 8704 B (fp16 partials)
    __shared__ float Lw[4][16];

    const int b = blockIdx.z, h = blockIdx.y, n0 = blockIdx.x * 16;
    const int t = threadIdx.x;
    const int w = t >> 6, lane = t & 63, quad = lane >> 4, l16 = lane & 15;

    const _Float16* qp = Qp + ((size_t)b * Nn + n0 + l16) * 256 + h * 64 + quad * 8;
    const half8 qa0 = *(const half8*)(qp);
    const half8 qa1 = *(const half8*)(qp + 32);

    const _Float16* Kbase = Kp + (size_t)b * Nn * 256 + h * 64;
    const _Float16* Vbase = Vt + ((size_t)b * 256 + h * 64 + l16) * (size_t)Mm;
    const unsigned int* bmBase = bmask + ((size_t)b * Nn + n0 + quad * 4) * (Mm / 32);

    float lo[4] = {0.f, 0.f, 0.f, 0.f};
    f32x4 O[4] = {};

    const int mbeg = w * (Mm / 4);

    half8 kA[8], kB[8];

    auto loadK = [&](half8* kd, int m0) {
        #pragma unroll
        for (int mt = 0; mt < 4; ++mt) {
            const _Float16* kp = Kbase + (size_t)(m0 + mt * 16 + l16) * 256 + quad * 8;
            kd[mt * 2]     = *(const half8*)(kp);
            kd[mt * 2 + 1] = *(const half8*)(kp + 32);
        }
    };

    auto step = [&](const half8* kk, int m0) {
        // V loads first: independent of everything above; consumed only by
        // the PV MFMAs at the bottom -> latency hides under QK+exp+Ps.
        half8 vv[8];
        #pragma unroll
        for (int dt = 0; dt < 4; ++dt) {
            const _Float16* vp = Vbase + (size_t)(dt * 16) * Mm + m0 + quad * 8;
            vv[dt * 2]     = *(const half8*)(vp);
            vv[dt * 2 + 1] = *(const half8*)(vp + 32);
        }
        uint2 bmv[4];
        #pragma unroll
        for (int reg = 0; reg < 4; ++reg)
            bmv[reg] = *(const uint2*)(bmBase + (size_t)reg * (Mm / 32) + (m0 >> 5));

        f32x4 S[4];
        #pragma unroll
        for (int mt = 0; mt < 4; ++mt) {
            f32x4 z = {0.f, 0.f, 0.f, 0.f};
            z = __builtin_amdgcn_mfma_f32_16x16x32_f16(qa0, kk[mt * 2], z, 0, 0, 0);
            z = __builtin_amdgcn_mfma_f32_16x16x32_f16(qa1, kk[mt * 2 + 1], z, 0, 0, 0);
            S[mt] = z;
        }

        // static-max softmax: p = bit ? exp(S/8) : 0
        float p[4][4];
        #pragma unroll
        for (int reg = 0; reg < 4; ++reg) {
            const unsigned losh = bmv[reg].x >> l16;   // bit0 -> mt0, bit16 -> mt1
            const unsigned hish = bmv[reg].y >> l16;   // bit0 -> mt2, bit16 -> mt3
            p[0][reg] = (losh & 1u)         ? __expf(S[0][reg] * 0.125f) : 0.f;
            p[1][reg] = ((losh >> 16) & 1u) ? __expf(S[1][reg] * 0.125f) : 0.f;
            p[2][reg] = (hish & 1u)         ? __expf(S[2][reg] * 0.125f) : 0.f;
            p[3][reg] = ((hish >> 16) & 1u) ? __expf(S[3][reg] * 0.125f) : 0.f;
        }
        #pragma unroll
        for (int reg = 0; reg < 4; ++reg)
            lo[reg] += (p[0][reg] + p[1][reg]) + (p[2][reg] + p[3][reg]);

        #pragma unroll
        for (int mt = 0; mt < 4; ++mt)
            #pragma unroll
            for (int reg = 0; reg < 4; ++reg)
                Ps[w][quad * 4 + reg][mt * 16 + l16] = (_Float16)p[mt][reg];
        __asm__ volatile("s_waitcnt lgkmcnt(0)" ::: "memory");
        half8 pa0 = *(const half8*)&Ps[w][l16][quad * 8];
        half8 pa1 = *(const half8*)&Ps[w][l16][32 + quad * 8];

        #pragma unroll
        for (int dt = 0; dt < 4; ++dt) {
            O[dt] = __builtin_amdgcn_mfma_f32_16x16x32_f16(pa0, vv[dt * 2], O[dt], 0, 0, 0);
            O[dt] = __builtin_amdgcn_mfma_f32_16x16x32_f16(pa1, vv[dt * 2 + 1], O[dt], 0, 0, 0);
        }
    };

    loadK(kA, mbeg);
    #pragma unroll 1
    for (int ii = 0; ii < 4; ++ii) {
        const int m0A = mbeg + ii * 128;
        loadK(kB, m0A + 64);           // prefetch step B's K across step A
        step(kA, m0A);
        if (ii < 3) loadK(kA, m0A + 128);  // prefetch next A across step B
        step(kB, m0A + 64);
    }

    // one cross-lane sum of l (16-lane groups), once per kernel
    #pragma unroll
    for (int reg = 0; reg < 4; ++reg) {
        #pragma unroll
        for (int off = 1; off < 16; off <<= 1)
            lo[reg] += __shfl_xor(lo[reg], off);
    }

    // wave partials -> LDS, scaled 1/16 for fp16 headroom (cancels in divide)
    #pragma unroll
    for (int dt = 0; dt < 4; ++dt)
        #pragma unroll
        for (int reg = 0; reg < 4; ++reg)
            Osw[w][quad * 4 + reg][dt * 16 + l16] = (_Float16)(O[dt][reg] * 0.0625f);
    if (l16 == 0) {
        #pragma unroll
        for (int reg = 0; reg < 4; ++reg)
            Lw[w][quad * 4 + reg] = lo[reg] * 0.0625f;
    }
    __syncthreads();

    // combine: shared implicit max (zero) across waves -> plain sums
    const int nrow = t >> 4, dseg = (t & 15) * 4;
    const float L = Lw[0][nrow] + Lw[1][nrow] + Lw[2][nrow] + Lw[3][nrow];
    const float inv = 1.0f / L;
    half4v outv;
    #pragma unroll
    for (int dd = 0; dd < 4; ++dd) {
        const int d = dseg + dd;
        float s = (float)Osw[0][nrow][d] + (float)Osw[1][nrow][d]
                + (float)Osw[2][nrow][d] + (float)Osw[3][nrow][d];
        outv[dd] = (_Float16)(s * inv);
    }
    *(half4v*)(msgp + ((size_t)b * Nn + n0 + nrow) * 256 + h * 64 + dseg) = outv;
}

// ---------------------------------------------------------------------------
extern "C" void kernel_launch(void* const* d_in, const int* in_sizes, int n_in,
                              void* d_out, int out_size, void* d_ws, size_t ws_size,
                              hipStream_t stream) {
    const float* x      = (const float*)d_in[0];
    const float* source = (const float*)d_in[1];
    const float* mask   = (const float*)d_in[2];
    const float* Wq = (const float*)d_in[3];
    const float* bq = (const float*)d_in[4];
    const float* Wk = (const float*)d_in[5];
    const float* bk = (const float*)d_in[6];
    const float* Wv = (const float*)d_in[7];
    const float* bv = (const float*)d_in[8];
    const float* Wm = (const float*)d_in[9];
    const float* bm = (const float*)d_in[10];
    const float* W1 = (const float*)d_in[11];
    const float* b1 = (const float*)d_in[12];
    const float* gamma = (const float*)d_in[13];
    const float* beta  = (const float*)d_in[14];
    const float* rmean = (const float*)d_in[15];
    const float* rvar  = (const float*)d_in[16];
    const float* W2 = (const float*)d_in[17];
    const float* b2 = (const float*)d_in[18];
    float* outp = (float*)d_out;

    // workspace layout (bytes)
    char* wsb = (char*)d_ws;
    _Float16* Yp   = (_Float16*)wsb;                       // [8192][512]  8 MB
    _Float16* Sp   = (_Float16*)(wsb + (8u << 20));        // [8192][256]  4 MB
    _Float16* Qp   = (_Float16*)(wsb + (12u << 20));       // [8192][256]  4 MB
    _Float16* Kp   = (_Float16*)(wsb + (16u << 20));       // [8192][256]  4 MB
    _Float16* Vt   = (_Float16*)(wsb + (20u << 20));       // [1024][2048] 4 MB
    _Float16* msgp = (_Float16*)(wsb + (24u << 20));       // [8192][256]  4 MB
    _Float16* Hp   = (_Float16*)(wsb + (28u << 20));       // [8192][512]  8 MB
    // bitmask lives in the Hp region (2 MB): dead before mlp1 writes Hp.
    unsigned long long* bmask = (unsigned long long*)(wsb + (28u << 20));
    char* wp = wsb + (36u << 20);
    _Float16* Wqp  = (_Float16*)wp;            wp += 256 * 256 * 2;
    _Float16* Wkvp = (_Float16*)wp;            wp += 512 * 256 * 2;
    _Float16* Wmp  = (_Float16*)wp;            wp += 256 * 256 * 2;
    _Float16* W1p  = (_Float16*)wp;            wp += 512 * 512 * 2;
    _Float16* W2p  = (_Float16*)wp;            wp += 256 * 512 * 2;
    float* bqp  = (float*)wp;                  wp += 256 * 4;
    float* bkvp = (float*)wp;                  wp += 512 * 4;
    float* b1f  = (float*)wp;                  wp += 512 * 4;

    prep_weights_kernel<<<3840, 256, 0, stream>>>(
        Wq, bq, Wk, bk, Wv, bv, Wm, W1, b1, gamma, beta, rmean, rvar, W2, mask,
        Wqp, bqp, Wkvp, bkvp, Wmp, W1p, b1f, W2p, bmask);

    dim3 gPrep(Nn / 64, Dd / 64, Bb * 2);
    prep_x_kernel<<<gPrep, 256, 0, stream>>>(x, source, Yp, Sp);

    // q projection: A=Yp (x cols 0..256, stride 512), out Qp [n][256]
    gemm16_kernel<<<dim3(NT / 32, 4), 64, 0, stream>>>(
        Yp, Wqp, bqp, Qp, nullptr, nullptr, 256, 512, 256, 0, 0);
    // k+v projections: A=Sp, out Kp (mode0) / Vt (mode1)
    gemm16_kernel<<<dim3(NT / 32, 8), 64, 0, stream>>>(
        Sp, Wkvp, bkvp, Kp, Vt, nullptr, 256, 256, 256, 1, 0);

    dim3 gAttn(Nn / 16, Hh, Bb);
    attn_mfma_kernel<<<gAttn, 256, 0, stream>>>(Qp, Kp, Vt,
                                                (const unsigned int*)bmask, msgp);

    // message projection: A=msgp, out -> Yp cols 256..512
    gemm16_kernel<<<dim3(NT / 32, 4), 64, 0, stream>>>(
        msgp, Wmp, bm, Yp + 256, nullptr, nullptr, 256, 256, 512, 0, 0);
    // MLP layer 1 (BN-folded, relu): A=Yp [n][512], out Hp [n][512]
    gemm16_kernel<<<dim3(NT / 32, 8), 64, 0, stream>>>(
        Yp, W1p, b1f, Hp, nullptr, nullptr, 512, 512, 512, 0, 1);
    // MLP layer 2: A=Hp, fp32 out [b][256][n]
    gemm16_kernel<<<dim3(NT / 32, 4), 64, 0, stream>>>(
        Hp, W2p, b2, nullptr, nullptr, outp, 512, 512, 0, 2, 0);
}

// Round 3
// 272.382 us; speedup vs baseline: 1.2962x; 1.2962x over previous
//
#include <hip/hip_runtime.h>

// Problem constants
constexpr int Bb = 4;     // batch
constexpr int Dd = 256;   // channels
constexpr int Nn = 2048;  // query positions
constexpr int Mm = 2048;  // source positions
constexpr int Hh = 4;     // heads
constexpr int D2 = 512;   // 2*D
constexpr int NT = Bb * Nn;  // 8192 total positions

#define FMAXV 3.402823466e38f

typedef _Float16 half8 __attribute__((ext_vector_type(8)));
typedef _Float16 half4v __attribute__((ext_vector_type(4)));
typedef float f32x4 __attribute__((ext_vector_type(4)));

// ---------------------------------------------------------------------------
// Weight prepack + mask->bitmask pack (unchanged from R1)
// ---------------------------------------------------------------------------
__global__ __launch_bounds__(256)
void prep_weights_kernel(const float* __restrict__ Wq, const float* __restrict__ bq,
                         const float* __restrict__ Wk, const float* __restrict__ bk,
                         const float* __restrict__ Wv, const float* __restrict__ bv,
                         const float* __restrict__ Wm,
                         const float* __restrict__ W1, const float* __restrict__ b1,
                         const float* __restrict__ gamma, const float* __restrict__ beta,
                         const float* __restrict__ rmean, const float* __restrict__ rvar,
                         const float* __restrict__ W2, const float* __restrict__ mask,
                         _Float16* __restrict__ Wqp, float* __restrict__ bqp,
                         _Float16* __restrict__ Wkvp, float* __restrict__ bkvp,
                         _Float16* __restrict__ Wmp,
                         _Float16* __restrict__ W1p, float* __restrict__ b1f,
                         _Float16* __restrict__ W2p,
                         unsigned long long* __restrict__ bmask) {
    const int r = blockIdx.x, t = threadIdx.x;
    if (r < 256) {
        const int h = r >> 6, d = r & 63, so = d * Hh + h;
        Wqp[r * 256 + t] = (_Float16)Wq[so * 256 + t];
        if (t == 0) bqp[r] = bq[so];
    } else if (r < 768) {
        const int rr = r - 256, part = rr >> 8, o = rr & 255;
        const int h = o >> 6, d = o & 63, so = d * Hh + h;
        const float* Ws = part ? Wv : Wk;
        const float* bs = part ? bv : bk;
        Wkvp[rr * 256 + t] = (_Float16)Ws[so * 256 + t];
        if (t == 0) bkvp[rr] = bs[so];
    } else if (r < 1024) {
        const int o = r - 768;
        const int h = t >> 6, d = t & 63, sk = d * Hh + h;
        Wmp[o * 256 + t] = (_Float16)Wm[o * 256 + sk];
    } else if (r < 1536) {
        const int o = r - 1024;
        const float s = gamma[o] * rsqrtf(rvar[o] + 1e-3f);
        W1p[o * 512 + t]       = (_Float16)(W1[o * 512 + t] * s);
        W1p[o * 512 + t + 256] = (_Float16)(W1[o * 512 + t + 256] * s);
        if (t == 0) b1f[o] = (b1[o] - rmean[o]) * s + beta[o];
    } else if (r < 1792) {
        const int o = r - 1536;
        W2p[o * 512 + t]       = (_Float16)W2[o * 512 + t];
        W2p[o * 512 + t + 256] = (_Float16)W2[o * 512 + t + 256];
    } else {
        // bitmask pack: 2048 blocks x 4 waves, one row of mask per wave.
        const int id = r - 1792;               // 0..2047
        const int w = t >> 6, lane = t & 63;
        const int row = id * 4 + w;            // 0..8191  (= b*Nn + n)
        const float* mrow = mask + (size_t)row * Mm;
        unsigned long long* brow = bmask + (size_t)row * (Mm / 64);
        #pragma unroll 4
        for (int word = 0; word < Mm / 64; ++word) {
            const float v = mrow[word * 64 + lane];
            const unsigned long long bits = __ballot(v > 0.f);
            if (lane == 0) brow[word] = bits;
        }
    }
}

// ---------------------------------------------------------------------------
// Activation prepack (unchanged)
// ---------------------------------------------------------------------------
__global__ __launch_bounds__(256)
void prep_x_kernel(const float* __restrict__ x, const float* __restrict__ source,
                   _Float16* __restrict__ Yp, _Float16* __restrict__ Sp) {
    __shared__ _Float16 Ts[64][72];
    const int z = blockIdx.z, b = z >> 1, which = z & 1;
    const float* src = which ? source : x;
    _Float16* dst = which ? Sp : Yp;
    const int stride = which ? 256 : 512;
    const int c0 = blockIdx.y * 64, n0 = blockIdx.x * 64;
    const int t = threadIdx.x;
    const int cl = t >> 2, np = (t & 3) * 16;
    const float* sp = src + ((size_t)b * Dd + c0 + cl) * Nn + n0 + np;
    #pragma unroll
    for (int i = 0; i < 4; ++i) {
        float4 v = *(const float4*)(sp + i * 4);
        Ts[np + i * 4 + 0][cl] = (_Float16)v.x;
        Ts[np + i * 4 + 1][cl] = (_Float16)v.y;
        Ts[np + i * 4 + 2][cl] = (_Float16)v.z;
        Ts[np + i * 4 + 3][cl] = (_Float16)v.w;
    }
    __syncthreads();
    const int nl = t >> 2, cp = (t & 3) * 16;
    half8 a0 = *(const half8*)&Ts[nl][cp];
    half8 a1 = *(const half8*)&Ts[nl][cp + 8];
    _Float16* dp = dst + ((size_t)b * Nn + n0 + nl) * stride + c0 + cp;
    *(half8*)dp = a0;
    *(half8*)(dp + 8) = a1;
}

// ---------------------------------------------------------------------------
// fp16 MFMA GEMM: R1's 64x64-tile structure (R2's 32x64 reverted — it was
// worse). New modeSel==3: fused Q/K/V projection in ONE dispatch (W rows
// 0..255=Q, 256..511=K, 512..767=V are contiguous in the workspace, as are
// the biases), blockIdx.y picks the part; A operand switches Yp/Sp.
// ---------------------------------------------------------------------------
__global__ __launch_bounds__(64)
void gemm16_kernel(const _Float16* __restrict__ A, const _Float16* __restrict__ A2,
                   const _Float16* __restrict__ W, const float* __restrict__ bias,
                   _Float16* __restrict__ dst0, _Float16* __restrict__ dst1,
                   _Float16* __restrict__ dst2, float* __restrict__ dstF,
                   int K, int sA, int sOut, int modeSel, int relu) {
    __shared__ _Float16 Es[16][72];
    const int lane = threadIdx.x & 63, quad = lane >> 4, l16 = lane & 15;
    const int n0 = blockIdx.x * 64;
    const int og0 = blockIdx.y * 64;

    int mode = 0, oloc0 = og0;
    const _Float16* Ab = A;
    int sAl = sA;
    _Float16* d0 = dst0;
    if (modeSel == 3) {
        if (blockIdx.y >= 4) {
            Ab = A2; sAl = 256;
            if (blockIdx.y < 8) { d0 = dst1; oloc0 = og0 - 256; }   // K part
            else { mode = 1; oloc0 = og0 - 512; }                   // V part
        }
    } else if (modeSel == 2) {
        mode = 2;
    }

    const _Float16* aRow[4];
    const _Float16* bRow[4];
    #pragma unroll
    for (int i = 0; i < 4; ++i)
        aRow[i] = Ab + (size_t)(n0 + i * 16 + l16) * sAl + quad * 8;
    #pragma unroll
    for (int j = 0; j < 4; ++j)
        bRow[j] = W + (size_t)(og0 + j * 16 + l16) * K + quad * 8;

    f32x4 acc[4][4] = {};
    half8 a0[4], b0[4], a1[4], b1[4];
    #pragma unroll
    for (int i = 0; i < 4; ++i) a0[i] = *(const half8*)(aRow[i]);
    #pragma unroll
    for (int j = 0; j < 4; ++j) b0[j] = *(const half8*)(bRow[j]);

    #pragma unroll 1
    for (int k0 = 0; k0 < K; k0 += 64) {
        #pragma unroll
        for (int i = 0; i < 4; ++i) a1[i] = *(const half8*)(aRow[i] + k0 + 32);
        #pragma unroll
        for (int j = 0; j < 4; ++j) b1[j] = *(const half8*)(bRow[j] + k0 + 32);
        #pragma unroll
        for (int i = 0; i < 4; ++i)
            #pragma unroll
            for (int j = 0; j < 4; ++j)
                acc[i][j] = __builtin_amdgcn_mfma_f32_16x16x32_f16(a0[i], b0[j], acc[i][j], 0, 0, 0);
        if (k0 + 64 < K) {
            #pragma unroll
            for (int i = 0; i < 4; ++i) a0[i] = *(const half8*)(aRow[i] + k0 + 64);
            #pragma unroll
            for (int j = 0; j < 4; ++j) b0[j] = *(const half8*)(bRow[j] + k0 + 64);
        }
        #pragma unroll
        for (int i = 0; i < 4; ++i)
            #pragma unroll
            for (int j = 0; j < 4; ++j)
                acc[i][j] = __builtin_amdgcn_mfma_f32_16x16x32_f16(a1[i], b1[j], acc[i][j], 0, 0, 0);
    }

    float bcol[4];
    #pragma unroll
    for (int j = 0; j < 4; ++j) bcol[j] = bias[og0 + j * 16 + l16];

    if (mode == 0) {
        #pragma unroll
        for (int i = 0; i < 4; ++i) {
            #pragma unroll
            for (int j = 0; j < 4; ++j)
                #pragma unroll
                for (int reg = 0; reg < 4; ++reg) {
                    float v = acc[i][j][reg] + bcol[j];
                    if (relu) v = fmaxf(v, 0.f);
                    Es[quad * 4 + reg][j * 16 + l16] = (_Float16)v;
                }
            __asm__ volatile("s_waitcnt lgkmcnt(0)" ::: "memory");
            const int row = lane & 15, oseg = (lane >> 4) * 16;
            half8 e0 = *(const half8*)&Es[row][oseg];
            half8 e1 = *(const half8*)&Es[row][oseg + 8];
            _Float16* dp = d0 + (size_t)(n0 + i * 16 + row) * sOut + oloc0 + oseg;
            *(half8*)dp = e0;
            *(half8*)(dp + 8) = e1;
            __asm__ volatile("s_waitcnt lgkmcnt(0)" ::: "memory");
        }
    } else if (mode == 1) {
        #pragma unroll
        for (int i = 0; i < 4; ++i) {
            const int ng = n0 + i * 16 + quad * 4;
            const int bidx = ng >> 11, m0 = ng & 2047;
            #pragma unroll
            for (int j = 0; j < 4; ++j) {
                const int o = oloc0 + j * 16 + l16;
                half4v pv;
                #pragma unroll
                for (int reg = 0; reg < 4; ++reg) pv[reg] = (_Float16)(acc[i][j][reg] + bcol[j]);
                *(half4v*)(dst2 + ((size_t)bidx * 256 + o) * (size_t)Mm + m0) = pv;
            }
        }
    } else {
        #pragma unroll
        for (int i = 0; i < 4; ++i) {
            const int ng = n0 + i * 16 + quad * 4;
            const int bidx = ng >> 11, m0 = ng & 2047;
            #pragma unroll
            for (int j = 0; j < 4; ++j) {
                const int o = og0 + j * 16 + l16;
                f32x4 v;
                #pragma unroll
                for (int reg = 0; reg < 4; ++reg) v[reg] = acc[i][j][reg] + bcol[j];
                *(f32x4*)(dstF + ((size_t)bidx * 256 + o) * (size_t)Nn + m0) = v;
            }
        }
    }
}

// ---------------------------------------------------------------------------
// MFMA attention R3: LDS-shared K/V tiles.
// Why: R1/R2 showed duration invariant to occupancy with all pipes <20% busy
// -> the limiter is per-CU L2 transaction throughput (each wave privately
// gather-loaded its K/V range: 4 MB + 65K cache-line transactions per CU).
// New structure: block = 64 q-rows, 4 waves n-split (one 16-row tile each),
// all waves sweep full M together; per 64-m step the block cooperatively
// stages K[64][64h] + V[64][64h] into double-buffered LDS (coalesced,
// global->reg issued early, ds_write after compute), waves read MFMA
// fragments from LDS. 4x less global traffic, and the cross-wave Osw/Lw
// combine epilogue disappears (each wave owns its rows).
// Grid (N/64, H, B) = 512 blocks, 256 thr. LDS 46 KB.
// ---------------------------------------------------------------------------
__global__ __launch_bounds__(256)
void attn_mfma_kernel(const _Float16* __restrict__ Qp, const _Float16* __restrict__ Kp,
                      const _Float16* __restrict__ Vt,
                      const unsigned int* __restrict__ bmask,
                      _Float16* __restrict__ msgp) {
    __shared__ __align__(16) _Float16 Ks[2][64][72];   // 18432 B
    __shared__ __align__(16) _Float16 Vs[2][64][72];   // 18432 B
    __shared__ __align__(16) _Float16 Ps[4][16][72];   //  9216 B

    const int b = blockIdx.z, h = blockIdx.y, n0 = blockIdx.x * 64;
    const int t = threadIdx.x;
    const int w = t >> 6, lane = t & 63, quad = lane >> 4, l16 = lane & 15;

    // per-wave Q fragment: rows n0 + w*16 + l16
    const _Float16* qp = Qp + ((size_t)b * Nn + n0 + w * 16 + l16) * 256 + h * 64 + quad * 8;
    const half8 qa0 = *(const half8*)(qp);
    const half8 qa1 = *(const half8*)(qp + 32);

    // cooperative staging: thread t covers row sr (0..63), 16-half chunk sc
    const _Float16* Kstg = Kp + (size_t)b * Nn * 256 + h * 64;
    const _Float16* Vstg = Vt + ((size_t)b * 256 + h * 64) * (size_t)Mm;
    const int sr = t >> 2, sc = (t & 3) * 16;

    const unsigned int* bmBase = bmask + ((size_t)b * Nn + n0 + w * 16 + quad * 4) * (Mm / 32);

    float lo[4] = {0.f, 0.f, 0.f, 0.f};
    f32x4 O[4] = {};

    half8 sk0, sk1, sv0, sv1;
    auto stage_load = [&](int m0) {
        const _Float16* ks = Kstg + (size_t)(m0 + sr) * 256 + sc;
        sk0 = *(const half8*)(ks);
        sk1 = *(const half8*)(ks + 8);
        const _Float16* vs = Vstg + (size_t)sr * Mm + m0 + sc;
        sv0 = *(const half8*)(vs);
        sv1 = *(const half8*)(vs + 8);
    };
    auto stage_write = [&](int buf) {
        *(half8*)&Ks[buf][sr][sc]     = sk0;
        *(half8*)&Ks[buf][sr][sc + 8] = sk1;
        *(half8*)&Vs[buf][sr][sc]     = sv0;
        *(half8*)&Vs[buf][sr][sc + 8] = sv1;
    };

    stage_load(0);
    stage_write(0);
    __syncthreads();

    #pragma unroll 1
    for (int it = 0; it < Mm / 64; ++it) {
        const int m0 = it * 64, cur = it & 1;
        if (it < Mm / 64 - 1) stage_load(m0 + 64);   // issue next tile early

        uint2 bmv[4];
        #pragma unroll
        for (int reg = 0; reg < 4; ++reg)
            bmv[reg] = *(const uint2*)(bmBase + (size_t)reg * (Mm / 32) + (m0 >> 5));

        f32x4 S[4];
        #pragma unroll
        for (int mt = 0; mt < 4; ++mt) {
            half8 k0 = *(const half8*)&Ks[cur][mt * 16 + l16][quad * 8];
            half8 k1 = *(const half8*)&Ks[cur][mt * 16 + l16][32 + quad * 8];
            f32x4 z = {0.f, 0.f, 0.f, 0.f};
            z = __builtin_amdgcn_mfma_f32_16x16x32_f16(qa0, k0, z, 0, 0, 0);
            z = __builtin_amdgcn_mfma_f32_16x16x32_f16(qa1, k1, z, 0, 0, 0);
            S[mt] = z;
        }

        // static-max softmax: p = bit ? exp(S/8) : 0
        float p[4][4];
        #pragma unroll
        for (int reg = 0; reg < 4; ++reg) {
            const unsigned losh = bmv[reg].x >> l16;   // bit0 -> mt0, bit16 -> mt1
            const unsigned hish = bmv[reg].y >> l16;   // bit0 -> mt2, bit16 -> mt3
            p[0][reg] = (losh & 1u)         ? __expf(S[0][reg] * 0.125f) : 0.f;
            p[1][reg] = ((losh >> 16) & 1u) ? __expf(S[1][reg] * 0.125f) : 0.f;
            p[2][reg] = (hish & 1u)         ? __expf(S[2][reg] * 0.125f) : 0.f;
            p[3][reg] = ((hish >> 16) & 1u) ? __expf(S[3][reg] * 0.125f) : 0.f;
        }
        #pragma unroll
        for (int reg = 0; reg < 4; ++reg)
            lo[reg] += (p[0][reg] + p[1][reg]) + (p[2][reg] + p[3][reg]);

        #pragma unroll
        for (int mt = 0; mt < 4; ++mt)
            #pragma unroll
            for (int reg = 0; reg < 4; ++reg)
                Ps[w][quad * 4 + reg][mt * 16 + l16] = (_Float16)p[mt][reg];
        __asm__ volatile("s_waitcnt lgkmcnt(0)" ::: "memory");
        half8 pa0 = *(const half8*)&Ps[w][l16][quad * 8];
        half8 pa1 = *(const half8*)&Ps[w][l16][32 + quad * 8];

        #pragma unroll
        for (int dt = 0; dt < 4; ++dt) {
            half8 v0 = *(const half8*)&Vs[cur][dt * 16 + l16][quad * 8];
            half8 v1 = *(const half8*)&Vs[cur][dt * 16 + l16][32 + quad * 8];
            O[dt] = __builtin_amdgcn_mfma_f32_16x16x32_f16(pa0, v0, O[dt], 0, 0, 0);
            O[dt] = __builtin_amdgcn_mfma_f32_16x16x32_f16(pa1, v1, O[dt], 0, 0, 0);
        }

        if (it < Mm / 64 - 1) stage_write(cur ^ 1);  // fill other buffer
        __syncthreads();
    }

    // row-sum of l across the 16 lanes holding each row's m-slices
    #pragma unroll
    for (int reg = 0; reg < 4; ++reg) {
        float s = lo[reg];
        s += __shfl_xor(s, 1);
        s += __shfl_xor(s, 2);
        s += __shfl_xor(s, 4);
        s += __shfl_xor(s, 8);
        lo[reg] = 1.0f / s;
    }

    // direct store: row n0+w*16+quad*4+reg, col h*64+dt*16+l16 (no combine)
    _Float16* op = msgp + ((size_t)b * Nn + n0 + w * 16 + quad * 4) * 256 + h * 64 + l16;
    #pragma unroll
    for (int reg = 0; reg < 4; ++reg)
        #pragma unroll
        for (int dt = 0; dt < 4; ++dt)
            op[(size_t)reg * 256 + dt * 16] = (_Float16)(O[dt][reg] * lo[reg]);
}

// ---------------------------------------------------------------------------
extern "C" void kernel_launch(void* const* d_in, const int* in_sizes, int n_in,
                              void* d_out, int out_size, void* d_ws, size_t ws_size,
                              hipStream_t stream) {
    const float* x      = (const float*)d_in[0];
    const float* source = (const float*)d_in[1];
    const float* mask   = (const float*)d_in[2];
    const float* Wq = (const float*)d_in[3];
    const float* bq = (const float*)d_in[4];
    const float* Wk = (const float*)d_in[5];
    const float* bk = (const float*)d_in[6];
    const float* Wv = (const float*)d_in[7];
    const float* bv = (const float*)d_in[8];
    const float* Wm = (const float*)d_in[9];
    const float* bm = (const float*)d_in[10];
    const float* W1 = (const float*)d_in[11];
    const float* b1 = (const float*)d_in[12];
    const float* gamma = (const float*)d_in[13];
    const float* beta  = (const float*)d_in[14];
    const float* rmean = (const float*)d_in[15];
    const float* rvar  = (const float*)d_in[16];
    const float* W2 = (const float*)d_in[17];
    const float* b2 = (const float*)d_in[18];
    float* outp = (float*)d_out;

    // workspace layout (bytes)
    char* wsb = (char*)d_ws;
    _Float16* Yp   = (_Float16*)wsb;                       // [8192][512]  8 MB
    _Float16* Sp   = (_Float16*)(wsb + (8u << 20));        // [8192][256]  4 MB
    _Float16* Qp   = (_Float16*)(wsb + (12u << 20));       // [8192][256]  4 MB
    _Float16* Kp   = (_Float16*)(wsb + (16u << 20));       // [8192][256]  4 MB
    _Float16* Vt   = (_Float16*)(wsb + (20u << 20));       // [1024][2048] 4 MB
    _Float16* msgp = (_Float16*)(wsb + (24u << 20));       // [8192][256]  4 MB
    _Float16* Hp   = (_Float16*)(wsb + (28u << 20));       // [8192][512]  8 MB
    // bitmask lives in the Hp region (2 MB): dead before mlp1 writes Hp.
    unsigned long long* bmask = (unsigned long long*)(wsb + (28u << 20));
    char* wp = wsb + (36u << 20);
    _Float16* Wqp  = (_Float16*)wp;            wp += 256 * 256 * 2;   // rows 0..255  (Q)
    _Float16* Wkvp = (_Float16*)wp;            wp += 512 * 256 * 2;   // rows 256..767 (K,V)
    _Float16* Wmp  = (_Float16*)wp;            wp += 256 * 256 * 2;
    _Float16* W1p  = (_Float16*)wp;            wp += 512 * 512 * 2;
    _Float16* W2p  = (_Float16*)wp;            wp += 256 * 512 * 2;
    float* bqp  = (float*)wp;                  wp += 256 * 4;         // biases 0..255
    float* bkvp = (float*)wp;                  wp += 512 * 4;         // 256..767 (contiguous)
    float* b1f  = (float*)wp;                  wp += 512 * 4;

    prep_weights_kernel<<<3840, 256, 0, stream>>>(
        Wq, bq, Wk, bk, Wv, bv, Wm, W1, b1, gamma, beta, rmean, rvar, W2, mask,
        Wqp, bqp, Wkvp, bkvp, Wmp, W1p, b1f, W2p, bmask);

    dim3 gPrep(Nn / 64, Dd / 64, Bb * 2);
    prep_x_kernel<<<gPrep, 256, 0, stream>>>(x, source, Yp, Sp);

    // fused Q/K/V projection: one dispatch, 1536 blocks.
    // y 0..3: Q (A=Yp, sA=512 -> Qp); y 4..7: K (A=Sp -> Kp); y 8..11: V -> Vt
    gemm16_kernel<<<dim3(NT / 64, 12), 64, 0, stream>>>(
        Yp, Sp, Wqp, bqp, Qp, Kp, Vt, nullptr, 256, 512, 256, 3, 0);

    dim3 gAttn(Nn / 64, Hh, Bb);
    attn_mfma_kernel<<<gAttn, 256, 0, stream>>>(Qp, Kp, Vt,
                                                (const unsigned int*)bmask, msgp);

    // message projection: A=msgp, out -> Yp cols 256..512
    gemm16_kernel<<<dim3(NT / 64, 4), 64, 0, stream>>>(
        msgp, nullptr, Wmp, bm, Yp + 256, nullptr, nullptr, nullptr, 256, 256, 512, 0, 0);
    // MLP layer 1 (BN-folded, relu): A=Yp [n][512], out Hp [n][512]
    gemm16_kernel<<<dim3(NT / 64, 8), 64, 0, stream>>>(
        Yp, nullptr, W1p, b1f, Hp, nullptr, nullptr, nullptr, 512, 512, 512, 0, 1);
    // MLP layer 2: A=Hp, fp32 out [b][256][n]
    gemm16_kernel<<<dim3(NT / 64, 4), 64, 0, stream>>>(
        Hp, nullptr, W2p, b2, nullptr, nullptr, nullptr, outp, 512, 512, 0, 2, 0);
}

// Round 4
// 248.850 us; speedup vs baseline: 1.4188x; 1.0946x over previous
//
#include <hip/hip_runtime.h>

// Problem constants
constexpr int Bb = 4;     // batch
constexpr int Dd = 256;   // channels
constexpr int Nn = 2048;  // query positions
constexpr int Mm = 2048;  // source positions
constexpr int Hh = 4;     // heads
constexpr int D2 = 512;   // 2*D
constexpr int NT = Bb * Nn;  // 8192 total positions

#define FMAXV 3.402823466e38f

typedef _Float16 half8 __attribute__((ext_vector_type(8)));
typedef _Float16 half4v __attribute__((ext_vector_type(4)));
typedef float f32x4 __attribute__((ext_vector_type(4)));

typedef const __attribute__((address_space(1))) void* gas_p;
typedef __attribute__((address_space(3))) void* las_p;

__device__ __forceinline__ void gload16(const void* g, void* l) {
    // async global->LDS, 16B per lane; LDS dest = wave-uniform base + lane*16
    __builtin_amdgcn_global_load_lds((gas_p)g, (las_p)l, 16, 0, 0);
}

// ---------------------------------------------------------------------------
// Weight prepack + mask->bitmask pack (unchanged from R1)
// ---------------------------------------------------------------------------
__global__ __launch_bounds__(256)
void prep_weights_kernel(const float* __restrict__ Wq, const float* __restrict__ bq,
                         const float* __restrict__ Wk, const float* __restrict__ bk,
                         const float* __restrict__ Wv, const float* __restrict__ bv,
                         const float* __restrict__ Wm,
                         const float* __restrict__ W1, const float* __restrict__ b1,
                         const float* __restrict__ gamma, const float* __restrict__ beta,
                         const float* __restrict__ rmean, const float* __restrict__ rvar,
                         const float* __restrict__ W2, const float* __restrict__ mask,
                         _Float16* __restrict__ Wqp, float* __restrict__ bqp,
                         _Float16* __restrict__ Wkvp, float* __restrict__ bkvp,
                         _Float16* __restrict__ Wmp,
                         _Float16* __restrict__ W1p, float* __restrict__ b1f,
                         _Float16* __restrict__ W2p,
                         unsigned long long* __restrict__ bmask) {
    const int r = blockIdx.x, t = threadIdx.x;
    if (r < 256) {
        const int h = r >> 6, d = r & 63, so = d * Hh + h;
        Wqp[r * 256 + t] = (_Float16)Wq[so * 256 + t];
        if (t == 0) bqp[r] = bq[so];
    } else if (r < 768) {
        const int rr = r - 256, part = rr >> 8, o = rr & 255;
        const int h = o >> 6, d = o & 63, so = d * Hh + h;
        const float* Ws = part ? Wv : Wk;
        const float* bs = part ? bv : bk;
        Wkvp[rr * 256 + t] = (_Float16)Ws[so * 256 + t];
        if (t == 0) bkvp[rr] = bs[so];
    } else if (r < 1024) {
        const int o = r - 768;
        const int h = t >> 6, d = t & 63, sk = d * Hh + h;
        Wmp[o * 256 + t] = (_Float16)Wm[o * 256 + sk];
    } else if (r < 1536) {
        const int o = r - 1024;
        const float s = gamma[o] * rsqrtf(rvar[o] + 1e-3f);
        W1p[o * 512 + t]       = (_Float16)(W1[o * 512 + t] * s);
        W1p[o * 512 + t + 256] = (_Float16)(W1[o * 512 + t + 256] * s);
        if (t == 0) b1f[o] = (b1[o] - rmean[o]) * s + beta[o];
    } else if (r < 1792) {
        const int o = r - 1536;
        W2p[o * 512 + t]       = (_Float16)W2[o * 512 + t];
        W2p[o * 512 + t + 256] = (_Float16)W2[o * 512 + t + 256];
    } else {
        // bitmask pack: 2048 blocks x 4 waves, one row of mask per wave.
        const int id = r - 1792;               // 0..2047
        const int w = t >> 6, lane = t & 63;
        const int row = id * 4 + w;            // 0..8191  (= b*Nn + n)
        const float* mrow = mask + (size_t)row * Mm;
        unsigned long long* brow = bmask + (size_t)row * (Mm / 64);
        #pragma unroll 4
        for (int word = 0; word < Mm / 64; ++word) {
            const float v = mrow[word * 64 + lane];
            const unsigned long long bits = __ballot(v > 0.f);
            if (lane == 0) brow[word] = bits;
        }
    }
}

// ---------------------------------------------------------------------------
// Activation prepack (unchanged)
// ---------------------------------------------------------------------------
__global__ __launch_bounds__(256)
void prep_x_kernel(const float* __restrict__ x, const float* __restrict__ source,
                   _Float16* __restrict__ Yp, _Float16* __restrict__ Sp) {
    __shared__ _Float16 Ts[64][72];
    const int z = blockIdx.z, b = z >> 1, which = z & 1;
    const float* src = which ? source : x;
    _Float16* dst = which ? Sp : Yp;
    const int stride = which ? 256 : 512;
    const int c0 = blockIdx.y * 64, n0 = blockIdx.x * 64;
    const int t = threadIdx.x;
    const int cl = t >> 2, np = (t & 3) * 16;
    const float* sp = src + ((size_t)b * Dd + c0 + cl) * Nn + n0 + np;
    #pragma unroll
    for (int i = 0; i < 4; ++i) {
        float4 v = *(const float4*)(sp + i * 4);
        Ts[np + i * 4 + 0][cl] = (_Float16)v.x;
        Ts[np + i * 4 + 1][cl] = (_Float16)v.y;
        Ts[np + i * 4 + 2][cl] = (_Float16)v.z;
        Ts[np + i * 4 + 3][cl] = (_Float16)v.w;
    }
    __syncthreads();
    const int nl = t >> 2, cp = (t & 3) * 16;
    half8 a0 = *(const half8*)&Ts[nl][cp];
    half8 a1 = *(const half8*)&Ts[nl][cp + 8];
    _Float16* dp = dst + ((size_t)b * Nn + n0 + nl) * stride + c0 + cp;
    *(half8*)dp = a0;
    *(half8*)(dp + 8) = a1;
}

// ---------------------------------------------------------------------------
// R4 GEMM: 4-wave 128x128 block, BK=64, double-buffered LDS staging via
// global_load_lds(16B) with XOR-swizzled (source+read) chunk layout so the
// strided ds_read_b128 fragment loads are bank-balanced (m97/m201 pattern).
// Why: R0-R3 showed the 1-wave 64x64 GEMM stuck at ~150us total — 1 wave/
// SIMD with per-iter 16-line row-gathers from cross-XCD-cold L2/L3 (~500cy
// exposed per iter). Staging shares A/B across 4 waves and keeps a
// continuous async prefetch in flight.
// Each wave computes a 64x64 quadrant (wr,wc); epilogues unchanged per wave.
// ---------------------------------------------------------------------------
__global__ __launch_bounds__(256)
void gemm4w_kernel(const _Float16* __restrict__ A, const _Float16* __restrict__ A2,
                   const _Float16* __restrict__ W, const float* __restrict__ bias,
                   _Float16* __restrict__ dst0, _Float16* __restrict__ dst1,
                   _Float16* __restrict__ dst2, float* __restrict__ dstF,
                   int K, int sA, int sOut, int modeSel, int relu) {
    __shared__ __align__(16) _Float16 As[2][128][64];   // 32 KB
    __shared__ __align__(16) _Float16 Bs[2][128][64];   // 32 KB
    __shared__ __align__(16) _Float16 Es[4][16][72];    //  9 KB

    const int t = threadIdx.x;
    const int w = t >> 6, lane = t & 63, quad = lane >> 4, l16 = lane & 15;
    const int wr = w >> 1, wc = w & 1;                  // wave quadrant
    const int n0 = blockIdx.x * 128;
    const int og0 = blockIdx.y * 128;

    int mode = 0, oloc0 = og0;
    const _Float16* Ab = A;
    int sAl = sA;
    _Float16* d0 = dst0;
    if (modeSel == 3) {
        const int part = blockIdx.y >> 1;               // 0=Q, 1=K, 2=V
        if (part == 1)      { Ab = A2; sAl = 256; d0 = dst1; oloc0 = og0 - 256; }
        else if (part == 2) { Ab = A2; sAl = 256; mode = 1; oloc0 = og0 - 512; }
    } else if (modeSel == 2) {
        mode = 2;
    }

    // staging geometry: thread t covers row c*32 + (t>>3), 16B slot (t&7).
    // swizzle: LDS slot s of row r holds source chunk s ^ (r&7).
    const int srow = t >> 3, sslot = t & 7;
    const int schunk = sslot ^ (srow & 7);              // (c*32)&7 == 0

    f32x4 acc[4][4] = {};

    const int nk = K / 64;
    int buf = 0;

    {   // prologue: stage tile 0
        #pragma unroll
        for (int c = 0; c < 4; ++c) {
            const int row = c * 32 + srow;
            gload16(Ab + (size_t)(n0 + row) * sAl + schunk * 8,
                    (_Float16*)As + c * 2048 + t * 8);
            gload16(W + (size_t)(og0 + row) * K + schunk * 8,
                    (_Float16*)Bs + c * 2048 + t * 8);
        }
        __asm__ volatile("s_waitcnt vmcnt(0)" ::: "memory");
        __syncthreads();
    }

    #pragma unroll 1
    for (int kt = 0; kt < nk; ++kt) {
        if (kt + 1 < nk) {
            const int k0 = (kt + 1) * 64, nb = buf ^ 1;
            #pragma unroll
            for (int c = 0; c < 4; ++c) {
                const int row = c * 32 + srow;
                gload16(Ab + (size_t)(n0 + row) * sAl + k0 + schunk * 8,
                        (_Float16*)As + nb * 8192 + c * 2048 + t * 8);
                gload16(W + (size_t)(og0 + row) * K + k0 + schunk * 8,
                        (_Float16*)Bs + nb * 8192 + c * 2048 + t * 8);
            }
        }
        #pragma unroll
        for (int ks = 0; ks < 2; ++ks) {
            const int csw = ((ks * 4 + quad) ^ (l16 & 7)) * 8;
            half8 af[4], bf[4];
            #pragma unroll
            for (int i = 0; i < 4; ++i)
                af[i] = *(const half8*)&As[buf][wr * 64 + i * 16 + l16][csw];
            #pragma unroll
            for (int j = 0; j < 4; ++j)
                bf[j] = *(const half8*)&Bs[buf][wc * 64 + j * 16 + l16][csw];
            #pragma unroll
            for (int i = 0; i < 4; ++i)
                #pragma unroll
                for (int j = 0; j < 4; ++j)
                    acc[i][j] = __builtin_amdgcn_mfma_f32_16x16x32_f16(af[i], bf[j], acc[i][j], 0, 0, 0);
        }
        if (kt + 1 < nk) {
            __asm__ volatile("s_waitcnt vmcnt(0)" ::: "memory");
            __syncthreads();
            buf ^= 1;
        }
    }

    float bcol[4];
    #pragma unroll
    for (int j = 0; j < 4; ++j) bcol[j] = bias[og0 + wc * 64 + j * 16 + l16];

    if (mode == 0) {
        #pragma unroll
        for (int i = 0; i < 4; ++i) {
            #pragma unroll
            for (int j = 0; j < 4; ++j)
                #pragma unroll
                for (int reg = 0; reg < 4; ++reg) {
                    float v = acc[i][j][reg] + bcol[j];
                    if (relu) v = fmaxf(v, 0.f);
                    Es[w][quad * 4 + reg][j * 16 + l16] = (_Float16)v;
                }
            __asm__ volatile("s_waitcnt lgkmcnt(0)" ::: "memory");
            const int row = lane & 15, oseg = (lane >> 4) * 16;
            half8 e0 = *(const half8*)&Es[w][row][oseg];
            half8 e1 = *(const half8*)&Es[w][row][oseg + 8];
            _Float16* dp = d0 + (size_t)(n0 + wr * 64 + i * 16 + row) * sOut
                         + oloc0 + wc * 64 + oseg;
            *(half8*)dp = e0;
            *(half8*)(dp + 8) = e1;
            __asm__ volatile("s_waitcnt lgkmcnt(0)" ::: "memory");
        }
    } else if (mode == 1) {
        #pragma unroll
        for (int i = 0; i < 4; ++i) {
            const int ng = n0 + wr * 64 + i * 16 + quad * 4;
            const int bidx = ng >> 11, m0 = ng & 2047;
            #pragma unroll
            for (int j = 0; j < 4; ++j) {
                const int o = oloc0 + wc * 64 + j * 16 + l16;
                half4v pv;
                #pragma unroll
                for (int reg = 0; reg < 4; ++reg) pv[reg] = (_Float16)(acc[i][j][reg] + bcol[j]);
                *(half4v*)(dst2 + ((size_t)bidx * 256 + o) * (size_t)Mm + m0) = pv;
            }
        }
    } else {
        #pragma unroll
        for (int i = 0; i < 4; ++i) {
            const int ng = n0 + wr * 64 + i * 16 + quad * 4;
            const int bidx = ng >> 11, m0 = ng & 2047;
            #pragma unroll
            for (int j = 0; j < 4; ++j) {
                const int o = og0 + wc * 64 + j * 16 + l16;
                f32x4 v;
                #pragma unroll
                for (int reg = 0; reg < 4; ++reg) v[reg] = acc[i][j][reg] + bcol[j];
                *(f32x4*)(dstF + ((size_t)bidx * 256 + o) * (size_t)Nn + m0) = v;
            }
        }
    }
}

// ---------------------------------------------------------------------------
// MFMA attention R3 (unchanged): LDS-shared K/V tiles, static-max softmax,
// bitmask. Grid (N/64, H, B) = 512 blocks, 256 thr. LDS 46 KB.
// ---------------------------------------------------------------------------
__global__ __launch_bounds__(256)
void attn_mfma_kernel(const _Float16* __restrict__ Qp, const _Float16* __restrict__ Kp,
                      const _Float16* __restrict__ Vt,
                      const unsigned int* __restrict__ bmask,
                      _Float16* __restrict__ msgp) {
    __shared__ __align__(16) _Float16 Ks[2][64][72];   // 18432 B
    __shared__ __align__(16) _Float16 Vs[2][64][72];   // 18432 B
    __shared__ __align__(16) _Float16 Ps[4][16][72];   //  9216 B

    const int b = blockIdx.z, h = blockIdx.y, n0 = blockIdx.x * 64;
    const int t = threadIdx.x;
    const int w = t >> 6, lane = t & 63, quad = lane >> 4, l16 = lane & 15;

    const _Float16* qp = Qp + ((size_t)b * Nn + n0 + w * 16 + l16) * 256 + h * 64 + quad * 8;
    const half8 qa0 = *(const half8*)(qp);
    const half8 qa1 = *(const half8*)(qp + 32);

    const _Float16* Kstg = Kp + (size_t)b * Nn * 256 + h * 64;
    const _Float16* Vstg = Vt + ((size_t)b * 256 + h * 64) * (size_t)Mm;
    const int sr = t >> 2, sc = (t & 3) * 16;

    const unsigned int* bmBase = bmask + ((size_t)b * Nn + n0 + w * 16 + quad * 4) * (Mm / 32);

    float lo[4] = {0.f, 0.f, 0.f, 0.f};
    f32x4 O[4] = {};

    half8 sk0, sk1, sv0, sv1;
    auto stage_load = [&](int m0) {
        const _Float16* ks = Kstg + (size_t)(m0 + sr) * 256 + sc;
        sk0 = *(const half8*)(ks);
        sk1 = *(const half8*)(ks + 8);
        const _Float16* vs = Vstg + (size_t)sr * Mm + m0 + sc;
        sv0 = *(const half8*)(vs);
        sv1 = *(const half8*)(vs + 8);
    };
    auto stage_write = [&](int buf) {
        *(half8*)&Ks[buf][sr][sc]     = sk0;
        *(half8*)&Ks[buf][sr][sc + 8] = sk1;
        *(half8*)&Vs[buf][sr][sc]     = sv0;
        *(half8*)&Vs[buf][sr][sc + 8] = sv1;
    };

    stage_load(0);
    stage_write(0);
    __syncthreads();

    #pragma unroll 1
    for (int it = 0; it < Mm / 64; ++it) {
        const int m0 = it * 64, cur = it & 1;
        if (it < Mm / 64 - 1) stage_load(m0 + 64);

        uint2 bmv[4];
        #pragma unroll
        for (int reg = 0; reg < 4; ++reg)
            bmv[reg] = *(const uint2*)(bmBase + (size_t)reg * (Mm / 32) + (m0 >> 5));

        f32x4 S[4];
        #pragma unroll
        for (int mt = 0; mt < 4; ++mt) {
            half8 k0 = *(const half8*)&Ks[cur][mt * 16 + l16][quad * 8];
            half8 k1 = *(const half8*)&Ks[cur][mt * 16 + l16][32 + quad * 8];
            f32x4 z = {0.f, 0.f, 0.f, 0.f};
            z = __builtin_amdgcn_mfma_f32_16x16x32_f16(qa0, k0, z, 0, 0, 0);
            z = __builtin_amdgcn_mfma_f32_16x16x32_f16(qa1, k1, z, 0, 0, 0);
            S[mt] = z;
        }

        float p[4][4];
        #pragma unroll
        for (int reg = 0; reg < 4; ++reg) {
            const unsigned losh = bmv[reg].x >> l16;
            const unsigned hish = bmv[reg].y >> l16;
            p[0][reg] = (losh & 1u)         ? __expf(S[0][reg] * 0.125f) : 0.f;
            p[1][reg] = ((losh >> 16) & 1u) ? __expf(S[1][reg] * 0.125f) : 0.f;
            p[2][reg] = (hish & 1u)         ? __expf(S[2][reg] * 0.125f) : 0.f;
            p[3][reg] = ((hish >> 16) & 1u) ? __expf(S[3][reg] * 0.125f) : 0.f;
        }
        #pragma unroll
        for (int reg = 0; reg < 4; ++reg)
            lo[reg] += (p[0][reg] + p[1][reg]) + (p[2][reg] + p[3][reg]);

        #pragma unroll
        for (int mt = 0; mt < 4; ++mt)
            #pragma unroll
            for (int reg = 0; reg < 4; ++reg)
                Ps[w][quad * 4 + reg][mt * 16 + l16] = (_Float16)p[mt][reg];
        __asm__ volatile("s_waitcnt lgkmcnt(0)" ::: "memory");
        half8 pa0 = *(const half8*)&Ps[w][l16][quad * 8];
        half8 pa1 = *(const half8*)&Ps[w][l16][32 + quad * 8];

        #pragma unroll
        for (int dt = 0; dt < 4; ++dt) {
            half8 v0 = *(const half8*)&Vs[cur][dt * 16 + l16][quad * 8];
            half8 v1 = *(const half8*)&Vs[cur][dt * 16 + l16][32 + quad * 8];
            O[dt] = __builtin_amdgcn_mfma_f32_16x16x32_f16(pa0, v0, O[dt], 0, 0, 0);
            O[dt] = __builtin_amdgcn_mfma_f32_16x16x32_f16(pa1, v1, O[dt], 0, 0, 0);
        }

        if (it < Mm / 64 - 1) stage_write(cur ^ 1);
        __syncthreads();
    }

    #pragma unroll
    for (int reg = 0; reg < 4; ++reg) {
        float s = lo[reg];
        s += __shfl_xor(s, 1);
        s += __shfl_xor(s, 2);
        s += __shfl_xor(s, 4);
        s += __shfl_xor(s, 8);
        lo[reg] = 1.0f / s;
    }

    _Float16* op = msgp + ((size_t)b * Nn + n0 + w * 16 + quad * 4) * 256 + h * 64 + l16;
    #pragma unroll
    for (int reg = 0; reg < 4; ++reg)
        #pragma unroll
        for (int dt = 0; dt < 4; ++dt)
            op[(size_t)reg * 256 + dt * 16] = (_Float16)(O[dt][reg] * lo[reg]);
}

// ---------------------------------------------------------------------------
extern "C" void kernel_launch(void* const* d_in, const int* in_sizes, int n_in,
                              void* d_out, int out_size, void* d_ws, size_t ws_size,
                              hipStream_t stream) {
    const float* x      = (const float*)d_in[0];
    const float* source = (const float*)d_in[1];
    const float* mask   = (const float*)d_in[2];
    const float* Wq = (const float*)d_in[3];
    const float* bq = (const float*)d_in[4];
    const float* Wk = (const float*)d_in[5];
    const float* bk = (const float*)d_in[6];
    const float* Wv = (const float*)d_in[7];
    const float* bv = (const float*)d_in[8];
    const float* Wm = (const float*)d_in[9];
    const float* bm = (const float*)d_in[10];
    const float* W1 = (const float*)d_in[11];
    const float* b1 = (const float*)d_in[12];
    const float* gamma = (const float*)d_in[13];
    const float* beta  = (const float*)d_in[14];
    const float* rmean = (const float*)d_in[15];
    const float* rvar  = (const float*)d_in[16];
    const float* W2 = (const float*)d_in[17];
    const float* b2 = (const float*)d_in[18];
    float* outp = (float*)d_out;

    // workspace layout (bytes)
    char* wsb = (char*)d_ws;
    _Float16* Yp   = (_Float16*)wsb;                       // [8192][512]  8 MB
    _Float16* Sp   = (_Float16*)(wsb + (8u << 20));        // [8192][256]  4 MB
    _Float16* Qp   = (_Float16*)(wsb + (12u << 20));       // [8192][256]  4 MB
    _Float16* Kp   = (_Float16*)(wsb + (16u << 20));       // [8192][256]  4 MB
    _Float16* Vt   = (_Float16*)(wsb + (20u << 20));       // [1024][2048] 4 MB
    _Float16* msgp = (_Float16*)(wsb + (24u << 20));       // [8192][256]  4 MB
    _Float16* Hp   = (_Float16*)(wsb + (28u << 20));       // [8192][512]  8 MB
    // bitmask lives in the Hp region (2 MB): dead before mlp1 writes Hp.
    unsigned long long* bmask = (unsigned long long*)(wsb + (28u << 20));
    char* wp = wsb + (36u << 20);
    _Float16* Wqp  = (_Float16*)wp;            wp += 256 * 256 * 2;   // rows 0..255  (Q)
    _Float16* Wkvp = (_Float16*)wp;            wp += 512 * 256 * 2;   // rows 256..767 (K,V) — contiguous with Wqp
    _Float16* Wmp  = (_Float16*)wp;            wp += 256 * 256 * 2;
    _Float16* W1p  = (_Float16*)wp;            wp += 512 * 512 * 2;
    _Float16* W2p  = (_Float16*)wp;            wp += 256 * 512 * 2;
    float* bqp  = (float*)wp;                  wp += 256 * 4;         // biases 0..255
    float* bkvp = (float*)wp;                  wp += 512 * 4;         // 256..767 (contiguous)
    float* b1f  = (float*)wp;                  wp += 512 * 4;

    prep_weights_kernel<<<3840, 256, 0, stream>>>(
        Wq, bq, Wk, bk, Wv, bv, Wm, W1, b1, gamma, beta, rmean, rvar, W2, mask,
        Wqp, bqp, Wkvp, bkvp, Wmp, W1p, b1f, W2p, bmask);

    dim3 gPrep(Nn / 64, Dd / 64, Bb * 2);
    prep_x_kernel<<<gPrep, 256, 0, stream>>>(x, source, Yp, Sp);

    // fused Q/K/V projection: (64, 6) blocks of 128x128.
    // y 0,1: Q (A=Yp, sA=512 -> Qp); y 2,3: K (A=Sp -> Kp); y 4,5: V -> Vt
    gemm4w_kernel<<<dim3(NT / 128, 6), 256, 0, stream>>>(
        Yp, Sp, Wqp, bqp, Qp, Kp, Vt, nullptr, 256, 512, 256, 3, 0);

    dim3 gAttn(Nn / 64, Hh, Bb);
    attn_mfma_kernel<<<gAttn, 256, 0, stream>>>(Qp, Kp, Vt,
                                                (const unsigned int*)bmask, msgp);

    // message projection: A=msgp, out -> Yp cols 256..512
    gemm4w_kernel<<<dim3(NT / 128, 2), 256, 0, stream>>>(
        msgp, nullptr, Wmp, bm, Yp + 256, nullptr, nullptr, nullptr, 256, 256, 512, 0, 0);
    // MLP layer 1 (BN-folded, relu): A=Yp [n][512], out Hp [n][512]
    gemm4w_kernel<<<dim3(NT / 128, 4), 256, 0, stream>>>(
        Yp, nullptr, W1p, b1f, Hp, nullptr, nullptr, nullptr, 512, 512, 512, 0, 1);
    // MLP layer 2: A=Hp, fp32 out [b][256][n]
    gemm4w_kernel<<<dim3(NT / 128, 2), 256, 0, stream>>>(
        Hp, nullptr, W2p, b2, nullptr, nullptr, nullptr, outp, 512, 512, 0, 2, 0);
}

// Round 5
// 237.727 us; speedup vs baseline: 1.4852x; 1.0468x over previous
//
#include <hip/hip_runtime.h>

// Problem constants
constexpr int Bb = 4;     // batch
constexpr int Dd = 256;   // channels
constexpr int Nn = 2048;  // query positions
constexpr int Mm = 2048;  // source positions
constexpr int Hh = 4;     // heads
constexpr int D2 = 512;   // 2*D
constexpr int NT = Bb * Nn;  // 8192 total positions

#define FMAXV 3.402823466e38f

typedef _Float16 half8 __attribute__((ext_vector_type(8)));
typedef _Float16 half4v __attribute__((ext_vector_type(4)));
typedef float f32x4 __attribute__((ext_vector_type(4)));

typedef const __attribute__((address_space(1))) void* gas_p;
typedef __attribute__((address_space(3))) void* las_p;

__device__ __forceinline__ void gload16(const void* g, void* l) {
    __builtin_amdgcn_global_load_lds((gas_p)g, (las_p)l, 16, 0, 0);
}

// ---------------------------------------------------------------------------
// Fused prepack: weights + bitmask (blocks 0..3839) + activation transpose
// (blocks 3840..4863). One launch instead of two.
// ---------------------------------------------------------------------------
__global__ __launch_bounds__(256)
void prep_all_kernel(const float* __restrict__ Wq, const float* __restrict__ bq,
                     const float* __restrict__ Wk, const float* __restrict__ bk,
                     const float* __restrict__ Wv, const float* __restrict__ bv,
                     const float* __restrict__ Wm,
                     const float* __restrict__ W1, const float* __restrict__ b1,
                     const float* __restrict__ gamma, const float* __restrict__ beta,
                     const float* __restrict__ rmean, const float* __restrict__ rvar,
                     const float* __restrict__ W2, const float* __restrict__ mask,
                     const float* __restrict__ x, const float* __restrict__ source,
                     _Float16* __restrict__ Wqp, float* __restrict__ bqp,
                     _Float16* __restrict__ Wkvp, float* __restrict__ bkvp,
                     _Float16* __restrict__ Wmp,
                     _Float16* __restrict__ W1p, float* __restrict__ b1f,
                     _Float16* __restrict__ W2p,
                     unsigned long long* __restrict__ bmask,
                     _Float16* __restrict__ Yp, _Float16* __restrict__ Sp) {
    const int r = blockIdx.x, t = threadIdx.x;
    if (r < 256) {
        const int h = r >> 6, d = r & 63, so = d * Hh + h;
        Wqp[r * 256 + t] = (_Float16)Wq[so * 256 + t];
        if (t == 0) bqp[r] = bq[so];
    } else if (r < 768) {
        const int rr = r - 256, part = rr >> 8, o = rr & 255;
        const int h = o >> 6, d = o & 63, so = d * Hh + h;
        const float* Ws = part ? Wv : Wk;
        const float* bs = part ? bv : bk;
        Wkvp[rr * 256 + t] = (_Float16)Ws[so * 256 + t];
        if (t == 0) bkvp[rr] = bs[so];
    } else if (r < 1024) {
        const int o = r - 768;
        const int h = t >> 6, d = t & 63, sk = d * Hh + h;
        Wmp[o * 256 + t] = (_Float16)Wm[o * 256 + sk];
    } else if (r < 1536) {
        const int o = r - 1024;
        const float s = gamma[o] * rsqrtf(rvar[o] + 1e-3f);
        W1p[o * 512 + t]       = (_Float16)(W1[o * 512 + t] * s);
        W1p[o * 512 + t + 256] = (_Float16)(W1[o * 512 + t + 256] * s);
        if (t == 0) b1f[o] = (b1[o] - rmean[o]) * s + beta[o];
    } else if (r < 1792) {
        const int o = r - 1536;
        W2p[o * 512 + t]       = (_Float16)W2[o * 512 + t];
        W2p[o * 512 + t + 256] = (_Float16)W2[o * 512 + t + 256];
    } else if (r < 3840) {
        const int id = r - 1792;               // 0..2047
        const int w = t >> 6, lane = t & 63;
        const int row = id * 4 + w;            // 0..8191
        const float* mrow = mask + (size_t)row * Mm;
        unsigned long long* brow = bmask + (size_t)row * (Mm / 64);
        #pragma unroll 4
        for (int word = 0; word < Mm / 64; ++word) {
            const float v = mrow[word * 64 + lane];
            const unsigned long long bits = __ballot(v > 0.f);
            if (lane == 0) brow[word] = bits;
        }
    } else {
        // activation transpose (ex prep_x): px decomposes the old 3D grid
        __shared__ _Float16 Ts[64][72];
        const int px = r - 3840;
        const int n0 = (px & 31) * 64, c0 = ((px >> 5) & 3) * 64;
        const int z = px >> 7, b = z >> 1, which = z & 1;
        const float* src = which ? source : x;
        _Float16* dst = which ? Sp : Yp;
        const int stride = which ? 256 : 512;
        const int cl = t >> 2, np = (t & 3) * 16;
        const float* sp = src + ((size_t)b * Dd + c0 + cl) * Nn + n0 + np;
        #pragma unroll
        for (int i = 0; i < 4; ++i) {
            float4 v = *(const float4*)(sp + i * 4);
            Ts[np + i * 4 + 0][cl] = (_Float16)v.x;
            Ts[np + i * 4 + 1][cl] = (_Float16)v.y;
            Ts[np + i * 4 + 2][cl] = (_Float16)v.z;
            Ts[np + i * 4 + 3][cl] = (_Float16)v.w;
        }
        __syncthreads();
        const int nl = t >> 2, cp = (t & 3) * 16;
        half8 a0 = *(const half8*)&Ts[nl][cp];
        half8 a1 = *(const half8*)&Ts[nl][cp + 8];
        _Float16* dp = dst + ((size_t)b * Nn + n0 + nl) * stride + c0 + cp;
        *(half8*)dp = a0;
        *(half8*)(dp + 8) = a1;
    }
}

// ---------------------------------------------------------------------------
// R5 GEMM: BM=128, BN=64 per block (wave = 32x64, acc[2][4]) — doubles the
// tile count vs R4's 128x128 (QKV 768 / mlp1 512 blocks -> 2-3 blocks/CU;
// grids were the binding occupancy limit). Same gload_lds staging + XOR
// swizzle (src chunk = slot ^ (row&7), read col = want ^ (row&7)).
// oscale: Q projection pre-scales by 0.125 (exact pow2) so attn's softmax
// drops one VALU mul per exp.
// ---------------------------------------------------------------------------
__global__ __launch_bounds__(256)
void gemm4w_kernel(const _Float16* __restrict__ A, const _Float16* __restrict__ A2,
                   const _Float16* __restrict__ W, const float* __restrict__ bias,
                   _Float16* __restrict__ dst0, _Float16* __restrict__ dst1,
                   _Float16* __restrict__ dst2, float* __restrict__ dstF,
                   int K, int sA, int sOut, int modeSel, int relu, float oscale) {
    __shared__ __align__(16) _Float16 As[2 * 128 * 64];   // 32 KB
    __shared__ __align__(16) _Float16 Bs[2 * 64 * 64];    // 16 KB
    __shared__ __align__(16) _Float16 Es[4][16][72];      //  9 KB

    const int t = threadIdx.x;
    const int w = t >> 6, lane = t & 63, quad = lane >> 4, l16 = lane & 15;
    const int n0 = blockIdx.x * 128;
    const int og0 = blockIdx.y * 64;

    int mode = 0, oloc0 = og0;
    const _Float16* Ab = A;
    int sAl = sA;
    _Float16* d0 = dst0;
    float osc = oscale;
    if (modeSel == 3) {
        const int part = blockIdx.y >> 2;               // 0=Q, 1=K, 2=V
        if (part == 1)      { Ab = A2; sAl = 256; d0 = dst1; oloc0 = og0 - 256; osc = 1.0f; }
        else if (part == 2) { Ab = A2; sAl = 256; mode = 1; oloc0 = og0 - 512; osc = 1.0f; }
    } else if (modeSel == 2) {
        mode = 2;
    }

    const int srow = t >> 3, sslot = t & 7;
    const int schunk = sslot ^ (srow & 7);

    f32x4 acc[2][4] = {};
    const int nk = K / 64;
    int buf = 0;

    {   // prologue: stage tile 0
        #pragma unroll
        for (int c = 0; c < 4; ++c)
            gload16(Ab + (size_t)(n0 + c * 32 + srow) * sAl + schunk * 8,
                    As + c * 2048 + t * 8);
        #pragma unroll
        for (int c = 0; c < 2; ++c)
            gload16(W + (size_t)(og0 + c * 32 + srow) * K + schunk * 8,
                    Bs + c * 2048 + t * 8);
        __asm__ volatile("s_waitcnt vmcnt(0)" ::: "memory");
        __syncthreads();
    }

    #pragma unroll 1
    for (int kt = 0; kt < nk; ++kt) {
        if (kt + 1 < nk) {
            const int k0 = (kt + 1) * 64, nb = buf ^ 1;
            #pragma unroll
            for (int c = 0; c < 4; ++c)
                gload16(Ab + (size_t)(n0 + c * 32 + srow) * sAl + k0 + schunk * 8,
                        As + nb * 8192 + c * 2048 + t * 8);
            #pragma unroll
            for (int c = 0; c < 2; ++c)
                gload16(W + (size_t)(og0 + c * 32 + srow) * K + k0 + schunk * 8,
                        Bs + nb * 4096 + c * 2048 + t * 8);
        }
        #pragma unroll
        for (int ks = 0; ks < 2; ++ks) {
            const int csw = ((ks * 4 + quad) ^ (l16 & 7)) * 8;
            half8 af[2], bf[4];
            #pragma unroll
            for (int i = 0; i < 2; ++i)
                af[i] = *(const half8*)&As[buf * 8192 + (w * 32 + i * 16 + l16) * 64 + csw];
            #pragma unroll
            for (int j = 0; j < 4; ++j)
                bf[j] = *(const half8*)&Bs[buf * 4096 + (j * 16 + l16) * 64 + csw];
            #pragma unroll
            for (int i = 0; i < 2; ++i)
                #pragma unroll
                for (int j = 0; j < 4; ++j)
                    acc[i][j] = __builtin_amdgcn_mfma_f32_16x16x32_f16(af[i], bf[j], acc[i][j], 0, 0, 0);
        }
        if (kt + 1 < nk) {
            __asm__ volatile("s_waitcnt vmcnt(0)" ::: "memory");
            __syncthreads();
            buf ^= 1;
        }
    }

    float bcol[4];
    #pragma unroll
    for (int j = 0; j < 4; ++j) bcol[j] = bias[og0 + j * 16 + l16];

    if (mode == 0) {
        #pragma unroll
        for (int i = 0; i < 2; ++i) {
            #pragma unroll
            for (int j = 0; j < 4; ++j)
                #pragma unroll
                for (int reg = 0; reg < 4; ++reg) {
                    float v = (acc[i][j][reg] + bcol[j]) * osc;
                    if (relu) v = fmaxf(v, 0.f);
                    Es[w][quad * 4 + reg][j * 16 + l16] = (_Float16)v;
                }
            __asm__ volatile("s_waitcnt lgkmcnt(0)" ::: "memory");
            const int row = lane & 15, oseg = (lane >> 4) * 16;
            half8 e0 = *(const half8*)&Es[w][row][oseg];
            half8 e1 = *(const half8*)&Es[w][row][oseg + 8];
            _Float16* dp = d0 + (size_t)(n0 + w * 32 + i * 16 + row) * sOut + oloc0 + oseg;
            *(half8*)dp = e0;
            *(half8*)(dp + 8) = e1;
            __asm__ volatile("s_waitcnt lgkmcnt(0)" ::: "memory");
        }
    } else if (mode == 1) {
        #pragma unroll
        for (int i = 0; i < 2; ++i) {
            const int ng = n0 + w * 32 + i * 16 + quad * 4;
            const int bidx = ng >> 11, m0 = ng & 2047;
            #pragma unroll
            for (int j = 0; j < 4; ++j) {
                const int o = oloc0 + j * 16 + l16;
                half4v pv;
                #pragma unroll
                for (int reg = 0; reg < 4; ++reg) pv[reg] = (_Float16)(acc[i][j][reg] + bcol[j]);
                *(half4v*)(dst2 + ((size_t)bidx * 256 + o) * (size_t)Mm + m0) = pv;
            }
        }
    } else {
        #pragma unroll
        for (int i = 0; i < 2; ++i) {
            const int ng = n0 + w * 32 + i * 16 + quad * 4;
            const int bidx = ng >> 11, m0 = ng & 2047;
            #pragma unroll
            for (int j = 0; j < 4; ++j) {
                const int o = og0 + j * 16 + l16;
                f32x4 v;
                #pragma unroll
                for (int reg = 0; reg < 4; ++reg) v[reg] = acc[i][j][reg] + bcol[j];
                *(f32x4*)(dstF + ((size_t)bidx * 256 + o) * (size_t)Nn + m0) = v;
            }
        }
    }
}

// ---------------------------------------------------------------------------
// MFMA attention R5: m-split x2 across blocks + single-buffer LDS.
// Why: R4 counters — occupancy 19.6% = exactly 2 blocks/CU (grid 512 on 256
// CUs, grid-limited) with all pipes idle -> need more waves/SIMD. Static-max
// softmax makes cross-block combine trivial (O and L partials just ADD).
// Single-buffer K/V LDS (27 KB) -> 4 blocks/CU resident, 4 waves/SIMD.
// XCD-aware 1D grid: the 64 blocks sharing one (b,h)'s 512 KB K/V slice land
// on the same XCD's L2 (id%8 picks the bh pair).
// Q arrives pre-scaled by 0.125 -> p = __expf(S) (one less mul per exp).
// Writes unnormalized O (fp16, x1/16) + L partials; combine_kernel divides.
// Grid 1024 blocks, 256 thr. LDS 27 KB.
// ---------------------------------------------------------------------------
__global__ __launch_bounds__(256)
void attn_mfma_kernel(const _Float16* __restrict__ Qp, const _Float16* __restrict__ Kp,
                      const _Float16* __restrict__ Vt,
                      const unsigned int* __restrict__ bmask,
                      _Float16* __restrict__ Oa, _Float16* __restrict__ Ob,
                      float* __restrict__ La, float* __restrict__ Lb) {
    __shared__ __align__(16) _Float16 Ks[64][72];      // 9216 B
    __shared__ __align__(16) _Float16 Vs[64][72];      // 9216 B
    __shared__ __align__(16) _Float16 Ps[4][16][72];   // 9216 B

    // XCD-aware decomposition: id%8 = XCD slot -> bh pair
    const int id = blockIdx.x;
    const int xcd = id & 7, loc = id >> 3;             // loc 0..127
    const int bh = xcd * 2 + (loc >> 6);               // 0..15
    const int sub = loc & 63;
    const int mhalf = sub & 1;
    const int n0 = (sub >> 1) * 64;
    const int b = bh >> 2, h = bh & 3;

    const int t = threadIdx.x;
    const int w = t >> 6, lane = t & 63, quad = lane >> 4, l16 = lane & 15;

    const _Float16* qp = Qp + ((size_t)b * Nn + n0 + w * 16 + l16) * 256 + h * 64 + quad * 8;
    const half8 qa0 = *(const half8*)(qp);
    const half8 qa1 = *(const half8*)(qp + 32);

    const _Float16* Kstg = Kp + (size_t)b * Nn * 256 + h * 64;
    const _Float16* Vstg = Vt + ((size_t)b * 256 + h * 64) * (size_t)Mm;
    const int sr = t >> 2, sc = (t & 3) * 16;

    const unsigned int* bmBase = bmask + ((size_t)b * Nn + n0 + w * 16 + quad * 4) * (Mm / 32);

    _Float16* Od = mhalf ? Ob : Oa;
    float* Ld = mhalf ? Lb : La;
    const int mbeg = mhalf * (Mm / 2);

    float lo[4] = {0.f, 0.f, 0.f, 0.f};
    f32x4 O[4] = {};

    half8 sk0, sk1, sv0, sv1;
    auto stage_load = [&](int m0) {
        const _Float16* ks = Kstg + (size_t)(m0 + sr) * 256 + sc;
        sk0 = *(const half8*)(ks);
        sk1 = *(const half8*)(ks + 8);
        const _Float16* vs = Vstg + (size_t)sr * Mm + m0 + sc;
        sv0 = *(const half8*)(vs);
        sv1 = *(const half8*)(vs + 8);
    };
    auto stage_write = [&]() {
        *(half8*)&Ks[sr][sc]     = sk0;
        *(half8*)&Ks[sr][sc + 8] = sk1;
        *(half8*)&Vs[sr][sc]     = sv0;
        *(half8*)&Vs[sr][sc + 8] = sv1;
    };

    stage_load(mbeg);
    stage_write();
    __syncthreads();

    #pragma unroll 1
    for (int it = 0; it < (Mm / 2) / 64; ++it) {
        const int m0 = mbeg + it * 64;
        if (it < (Mm / 2) / 64 - 1) stage_load(m0 + 64);  // in flight under compute

        uint2 bmv[4];
        #pragma unroll
        for (int reg = 0; reg < 4; ++reg)
            bmv[reg] = *(const uint2*)(bmBase + (size_t)reg * (Mm / 32) + (m0 >> 5));

        f32x4 S[4];
        #pragma unroll
        for (int mt = 0; mt < 4; ++mt) {
            half8 k0 = *(const half8*)&Ks[mt * 16 + l16][quad * 8];
            half8 k1 = *(const half8*)&Ks[mt * 16 + l16][32 + quad * 8];
            f32x4 z = {0.f, 0.f, 0.f, 0.f};
            z = __builtin_amdgcn_mfma_f32_16x16x32_f16(qa0, k0, z, 0, 0, 0);
            z = __builtin_amdgcn_mfma_f32_16x16x32_f16(qa1, k1, z, 0, 0, 0);
            S[mt] = z;
        }

        // static-max softmax; Q pre-scaled by 0.125 -> p = bit ? exp(S) : 0
        float p[4][4];
        #pragma unroll
        for (int reg = 0; reg < 4; ++reg) {
            const unsigned losh = bmv[reg].x >> l16;
            const unsigned hish = bmv[reg].y >> l16;
            p[0][reg] = (losh & 1u)         ? __expf(S[0][reg]) : 0.f;
            p[1][reg] = ((losh >> 16) & 1u) ? __expf(S[1][reg]) : 0.f;
            p[2][reg] = (hish & 1u)         ? __expf(S[2][reg]) : 0.f;
            p[3][reg] = ((hish >> 16) & 1u) ? __expf(S[3][reg]) : 0.f;
        }
        #pragma unroll
        for (int reg = 0; reg < 4; ++reg)
            lo[reg] += (p[0][reg] + p[1][reg]) + (p[2][reg] + p[3][reg]);

        #pragma unroll
        for (int mt = 0; mt < 4; ++mt)
            #pragma unroll
            for (int reg = 0; reg < 4; ++reg)
                Ps[w][quad * 4 + reg][mt * 16 + l16] = (_Float16)p[mt][reg];
        __asm__ volatile("s_waitcnt lgkmcnt(0)" ::: "memory");
        half8 pa0 = *(const half8*)&Ps[w][l16][quad * 8];
        half8 pa1 = *(const half8*)&Ps[w][l16][32 + quad * 8];

        #pragma unroll
        for (int dt = 0; dt < 4; ++dt) {
            half8 v0 = *(const half8*)&Vs[dt * 16 + l16][quad * 8];
            half8 v1 = *(const half8*)&Vs[dt * 16 + l16][32 + quad * 8];
            O[dt] = __builtin_amdgcn_mfma_f32_16x16x32_f16(pa0, v0, O[dt], 0, 0, 0);
            O[dt] = __builtin_amdgcn_mfma_f32_16x16x32_f16(pa1, v1, O[dt], 0, 0, 0);
        }

        if (it < (Mm / 2) / 64 - 1) {
            __syncthreads();     // all waves done reading Ks/Vs
            stage_write();       // overwrite with next tile
            __syncthreads();     // writes visible
        }
    }

    #pragma unroll
    for (int reg = 0; reg < 4; ++reg) {
        float s = lo[reg];
        s += __shfl_xor(s, 1);
        s += __shfl_xor(s, 2);
        s += __shfl_xor(s, 4);
        s += __shfl_xor(s, 8);
        lo[reg] = s;
    }

    // unnormalized partials (x1/16 for fp16 headroom; cancels in combine)
    _Float16* op = Od + ((size_t)b * Nn + n0 + w * 16 + quad * 4) * 256 + h * 64 + l16;
    #pragma unroll
    for (int reg = 0; reg < 4; ++reg)
        #pragma unroll
        for (int dt = 0; dt < 4; ++dt)
            op[(size_t)reg * 256 + dt * 16] = (_Float16)(O[dt][reg] * 0.0625f);
    if (l16 == 0) {
        #pragma unroll
        for (int reg = 0; reg < 4; ++reg)
            Ld[((size_t)b * Nn + n0 + w * 16 + quad * 4 + reg) * 4 + h] = lo[reg] * 0.0625f;
    }
}

// ---------------------------------------------------------------------------
// Combine: msg_norm[n][c] = (Oa+Ob)/(La+Lb), c = h*64+d. 12 MB traffic.
// Grid 1024 x 256.
// ---------------------------------------------------------------------------
__global__ __launch_bounds__(256)
void combine_kernel(const _Float16* __restrict__ Oa, const _Float16* __restrict__ Ob,
                    const float* __restrict__ La, const float* __restrict__ Lb,
                    _Float16* __restrict__ out) {
    const int gid = blockIdx.x * 256 + threadIdx.x;    // 0..262143
    const int row = gid >> 5, chunk = gid & 31;
    const int h = chunk >> 3;
    const float L = La[row * 4 + h] + Lb[row * 4 + h];
    const float inv = 1.0f / L;
    half8 a = *(const half8*)(Oa + (size_t)row * 256 + chunk * 8);
    half8 c = *(const half8*)(Ob + (size_t)row * 256 + chunk * 8);
    half8 o;
    #pragma unroll
    for (int k = 0; k < 8; ++k)
        o[k] = (_Float16)(((float)a[k] + (float)c[k]) * inv);
    *(half8*)(out + (size_t)row * 256 + chunk * 8) = o;
}

// ---------------------------------------------------------------------------
extern "C" void kernel_launch(void* const* d_in, const int* in_sizes, int n_in,
                              void* d_out, int out_size, void* d_ws, size_t ws_size,
                              hipStream_t stream) {
    const float* x      = (const float*)d_in[0];
    const float* source = (const float*)d_in[1];
    const float* mask   = (const float*)d_in[2];
    const float* Wq = (const float*)d_in[3];
    const float* bq = (const float*)d_in[4];
    const float* Wk = (const float*)d_in[5];
    const float* bk = (const float*)d_in[6];
    const float* Wv = (const float*)d_in[7];
    const float* bv = (const float*)d_in[8];
    const float* Wm = (const float*)d_in[9];
    const float* bm = (const float*)d_in[10];
    const float* W1 = (const float*)d_in[11];
    const float* b1 = (const float*)d_in[12];
    const float* gamma = (const float*)d_in[13];
    const float* beta  = (const float*)d_in[14];
    const float* rmean = (const float*)d_in[15];
    const float* rvar  = (const float*)d_in[16];
    const float* W2 = (const float*)d_in[17];
    const float* b2 = (const float*)d_in[18];
    float* outp = (float*)d_out;

    // workspace layout (bytes)
    char* wsb = (char*)d_ws;
    _Float16* Yp   = (_Float16*)wsb;                       // [8192][512]  8 MB
    _Float16* Sp   = (_Float16*)(wsb + (8u << 20));        // [8192][256]  4 MB (src -> normalized msg)
    _Float16* Qp   = (_Float16*)(wsb + (12u << 20));       // [8192][256]  4 MB
    _Float16* Kp   = (_Float16*)(wsb + (16u << 20));       // [8192][256]  4 MB
    _Float16* Vt   = (_Float16*)(wsb + (20u << 20));       // [1024][2048] 4 MB
    _Float16* msgp = (_Float16*)(wsb + (24u << 20));       // [8192][256]  4 MB (O_A partial)
    _Float16* Hp   = (_Float16*)(wsb + (28u << 20));       // [8192][512]  8 MB (mlp1 out)
    // transients inside the Hp region (all dead before mlp1 writes Hp):
    unsigned long long* bmask = (unsigned long long*)(wsb + (28u << 20));  // 2 MB
    _Float16* Ob = (_Float16*)(wsb + (30u << 20));                          // 4 MB (O_B partial)
    float* La = (float*)(wsb + (34u << 20));                                // 128 KB
    float* Lb = (float*)(wsb + (34u << 20) + (128u << 10));                 // 128 KB
    char* wp = wsb + (36u << 20);
    _Float16* Wqp  = (_Float16*)wp;            wp += 256 * 256 * 2;   // rows 0..255  (Q)
    _Float16* Wkvp = (_Float16*)wp;            wp += 512 * 256 * 2;   // rows 256..767 (K,V)
    _Float16* Wmp  = (_Float16*)wp;            wp += 256 * 256 * 2;
    _Float16* W1p  = (_Float16*)wp;            wp += 512 * 512 * 2;
    _Float16* W2p  = (_Float16*)wp;            wp += 256 * 512 * 2;
    float* bqp  = (float*)wp;                  wp += 256 * 4;         // biases 0..255
    float* bkvp = (float*)wp;                  wp += 512 * 4;         // 256..767 (contiguous)
    float* b1f  = (float*)wp;                  wp += 512 * 4;

    // fused prepack (weights + bitmask + activation transpose)
    prep_all_kernel<<<4864, 256, 0, stream>>>(
        Wq, bq, Wk, bk, Wv, bv, Wm, W1, b1, gamma, beta, rmean, rvar, W2, mask,
        x, source, Wqp, bqp, Wkvp, bkvp, Wmp, W1p, b1f, W2p, bmask, Yp, Sp);

    // fused Q/K/V projection: (64, 12) blocks of 128x64.
    // y 0..3: Q (A=Yp, sA=512 -> Qp, pre-scaled 0.125); y 4..7: K -> Kp; y 8..11: V -> Vt
    gemm4w_kernel<<<dim3(NT / 128, 12), 256, 0, stream>>>(
        Yp, Sp, Wqp, bqp, Qp, Kp, Vt, nullptr, 256, 512, 256, 3, 0, 0.125f);

    attn_mfma_kernel<<<1024, 256, 0, stream>>>(Qp, Kp, Vt,
                                               (const unsigned int*)bmask,
                                               msgp, Ob, La, Lb);

    combine_kernel<<<1024, 256, 0, stream>>>(msgp, Ob, La, Lb, Sp);

    // message projection: A=Sp (normalized msg), out -> Yp cols 256..512
    gemm4w_kernel<<<dim3(NT / 128, 4), 256, 0, stream>>>(
        Sp, nullptr, Wmp, bm, Yp + 256, nullptr, nullptr, nullptr, 256, 256, 512, 0, 0, 1.0f);
    // MLP layer 1 (BN-folded, relu): A=Yp [n][512], out Hp [n][512]
    gemm4w_kernel<<<dim3(NT / 128, 8), 256, 0, stream>>>(
        Yp, nullptr, W1p, b1f, Hp, nullptr, nullptr, nullptr, 512, 512, 512, 0, 1, 1.0f);
    // MLP layer 2: A=Hp, fp32 out [b][256][n]
    gemm4w_kernel<<<dim3(NT / 128, 4), 256, 0, stream>>>(
        Hp, nullptr, W2p, b2, nullptr, nullptr, nullptr, outp, 512, 512, 0, 2, 0, 1.0f);
}